// Round 1
// baseline (830.301 us; speedup 1.0000x reference)
//
#include <hip/hip_runtime.h>

#define S_LEN 2048
#define E_DIM 1024
#define H_NUM 16

typedef __attribute__((ext_vector_type(8))) short s16x8;
typedef __attribute__((ext_vector_type(4))) float f32x4;

#define GA(p) ((__attribute__((address_space(1))) void*)(p))
#define LA(p) ((__attribute__((address_space(3))) void*)(p))

union cvt16 { int4 v; s16x8 s8; short e[8]; };

__device__ __forceinline__ short f2bf(float f) {
  union { float f; unsigned u; } v; v.f = f;
  unsigned r = v.u + 0x7FFFu + ((v.u >> 16) & 1u);
  return (short)(r >> 16);
}
__device__ __forceinline__ float bf2f(short s) {
  union { unsigned u; float f; } v; v.u = ((unsigned)(unsigned short)s) << 16;
  return v.f;
}

// ---------------------------------------------------------------------------
// Transpose + cast: src fp32 (R x C) -> dst bf16 (C x R), batched.
// ---------------------------------------------------------------------------
__global__ void transpose_cast(const float* __restrict__ src, short* __restrict__ dst,
                               int R, int C, long sbs, long dbs) {
  __shared__ float tile[32][33];
  const float* s = src + (long)blockIdx.z * sbs;
  short* d = dst + (long)blockIdx.z * dbs;
  int c0 = blockIdx.x * 32, r0 = blockIdx.y * 32;
  #pragma unroll
  for (int i = threadIdx.y; i < 32; i += 8)
    tile[i][threadIdx.x] = s[(long)(r0 + i) * C + c0 + threadIdx.x];
  __syncthreads();
  #pragma unroll
  for (int i = threadIdx.y; i < 32; i += 8)
    d[(long)(c0 + i) * R + r0 + threadIdx.x] = f2bf(tile[threadIdx.x][i]);
}

// ---------------------------------------------------------------------------
// Fused QKV projection GEMM: C[row, n] = sum_k A_seg[row, k] * Bt[n, k] + bias
// A: fp32 (8192 x 1024) (query/key/value per n-segment), Bt: bf16 (3072 x 1024)
// C: bf16 (8192 x 3072). Tile 128x128, BK=64.
// ---------------------------------------------------------------------------
__global__ __launch_bounds__(256, 3) void proj_gemm(
    const float* __restrict__ Aq, const float* __restrict__ Ak, const float* __restrict__ Av,
    const short* __restrict__ Bt,
    const float* __restrict__ bq, const float* __restrict__ bk, const float* __restrict__ bv,
    short* __restrict__ Cout) {
  __shared__ short Asub[128 * 64];
  __shared__ short Bsub[128 * 64];
  const int tid = threadIdx.x;
  const int w = tid >> 6, lane = tid & 63, ln = lane & 15, quad = lane >> 4;
  const int row0 = blockIdx.x * 128, n0 = blockIdx.y * 128;
  const int seg = n0 >> 10;
  const float* A = (seg == 0) ? Aq : ((seg == 1) ? Ak : Av);
  const float* bptr = (seg == 0) ? bq : ((seg == 1) ? bk : bv);
  const int nloc = n0 & 1023;
  const int wm = (w & 1) * 64, wn = (w >> 1) * 64;

  f32x4 acc[4][4];
  #pragma unroll
  for (int i = 0; i < 4; ++i)
    #pragma unroll
    for (int j = 0; j < 4; ++j) acc[i][j] = (f32x4){0.f, 0.f, 0.f, 0.f};

  for (int kt = 0; kt < 16; ++kt) {
    const int k0 = kt * 64;
    // B tile: async global->LDS, 16B/lane
    #pragma unroll
    for (int j = 0; j < 4; ++j) {
      int chunk = (w * 4 + j) * 64 + lane;
      int r = chunk >> 3, c = chunk & 7;
      const short* g = Bt + (long)(n0 + r) * 1024 + k0 + c * 8;
      __builtin_amdgcn_global_load_lds(GA(g), LA(&Bsub[(w * 4 + j) * 512]), 16, 0, 0);
    }
    // A tile: fp32 load, cvt to bf16, LDS store
    #pragma unroll
    for (int it = 0; it < 4; ++it) {
      int flat = (it * 256 + tid) * 8;
      int r = flat >> 6, c = flat & 63;
      const float* ga = A + (long)(row0 + r) * 1024 + k0 + c;
      float4 f0 = ((const float4*)ga)[0];
      float4 f1 = ((const float4*)ga)[1];
      s16x8 s8;
      s8[0] = f2bf(f0.x); s8[1] = f2bf(f0.y); s8[2] = f2bf(f0.z); s8[3] = f2bf(f0.w);
      s8[4] = f2bf(f1.x); s8[5] = f2bf(f1.y); s8[6] = f2bf(f1.z); s8[7] = f2bf(f1.w);
      *(s16x8*)&Asub[r * 64 + c] = s8;
    }
    __syncthreads();
    #pragma unroll
    for (int kk = 0; kk < 2; ++kk) {
      s16x8 af[4], bfr[4];
      #pragma unroll
      for (int i = 0; i < 4; ++i)
        af[i] = *(const s16x8*)&Asub[(wm + i * 16 + ln) * 64 + kk * 32 + quad * 8];
      #pragma unroll
      for (int j = 0; j < 4; ++j)
        bfr[j] = *(const s16x8*)&Bsub[(wn + j * 16 + ln) * 64 + kk * 32 + quad * 8];
      #pragma unroll
      for (int i = 0; i < 4; ++i)
        #pragma unroll
        for (int j = 0; j < 4; ++j)
          acc[i][j] = __builtin_amdgcn_mfma_f32_16x16x32_bf16(af[i], bfr[j], acc[i][j], 0, 0, 0);
    }
    __syncthreads();
  }
  // epilogue: + bias, bf16 store
  #pragma unroll
  for (int j = 0; j < 4; ++j) {
    float bvj = bptr[nloc + wn + j * 16 + ln];
    int n = n0 + wn + j * 16 + ln;
    #pragma unroll
    for (int i = 0; i < 4; ++i) {
      #pragma unroll
      for (int r = 0; r < 4; ++r) {
        int row = row0 + wm + i * 16 + quad * 4 + r;
        Cout[(long)row * 3072 + n] = f2bf(acc[i][j][r] + bvj);
      }
    }
  }
}

// ---------------------------------------------------------------------------
// Flash attention. Grid (S/128, H, B), block 256 (4 waves x 32 q-rows).
// qkv bf16 (8192 x 3072) [q | k | v per row], bias fp32 (2048 x 2048),
// concat bf16 (8192 x 1024). Q pre-scaled by 1/8.
// ---------------------------------------------------------------------------
__global__ __launch_bounds__(256, 3) void flash_attn(
    const short* __restrict__ qkv, const float* __restrict__ bias, short* __restrict__ concat) {
  __shared__ short Ks[64 * 64];    // (t, d)
  __shared__ short Vt[64 * 72];    // (d, t) padded
  __shared__ short Ps[128 * 72];   // (qrow, t) padded
  const int tid = threadIdx.x;
  const int w = tid >> 6, lane = tid & 63, ln = lane & 15, quad = lane >> 4;
  const int q0 = blockIdx.x * 128;
  const int h = blockIdx.y;
  const int bb = blockIdx.z;
  const float LOG2E = 1.4426950408889634f;

  // Q fragments in registers, pre-scaled by 0.125 (exact in bf16)
  s16x8 qf[2][2];
  #pragma unroll
  for (int i = 0; i < 2; ++i) {
    long qrow = (long)bb * S_LEN + q0 + w * 32 + i * 16 + ln;
    #pragma unroll
    for (int kk = 0; kk < 2; ++kk) {
      cvt16 u; u.v = *(const int4*)&qkv[qrow * 3072 + h * 64 + kk * 32 + quad * 8];
      s16x8 t;
      #pragma unroll
      for (int e = 0; e < 8; ++e) t[e] = f2bf(bf2f(u.e[e]) * 0.125f);
      qf[i][kk] = t;
    }
  }

  f32x4 o[2][4];
  float m_st[2][4], l_st[2][4];
  #pragma unroll
  for (int i = 0; i < 2; ++i) {
    #pragma unroll
    for (int nt = 0; nt < 4; ++nt) o[i][nt] = (f32x4){0.f, 0.f, 0.f, 0.f};
    #pragma unroll
    for (int r = 0; r < 4; ++r) { m_st[i][r] = -3.0e38f; l_st[i][r] = 0.f; }
  }

  const short* kbase0 = qkv + (long)bb * S_LEN * 3072 + 1024 + h * 64;
  const short* vbase0 = qkv + (long)bb * S_LEN * 3072 + 2048 + h * 64;

  for (int kv = 0; kv < 32; ++kv) {
    const int t0 = kv * 64;
    __syncthreads();  // previous iter's LDS reads complete
    // K tile async (8 KB)
    #pragma unroll
    for (int j = 0; j < 2; ++j) {
      int chunk = (w * 2 + j) * 64 + lane;
      int r = chunk >> 3, c = chunk & 7;
      const short* g = kbase0 + (long)(t0 + r) * 3072 + c * 8;
      __builtin_amdgcn_global_load_lds(GA(g), LA(&Ks[(w * 2 + j) * 512]), 16, 0, 0);
    }
    // V tile, transposed into Vt[d][t]
    #pragma unroll
    for (int it = 0; it < 2; ++it) {
      int chunk = it * 256 + tid;
      int t = chunk >> 3, d0 = (chunk & 7) * 8;
      cvt16 u; u.v = *(const int4*)(vbase0 + (long)(t0 + t) * 3072 + d0);
      #pragma unroll
      for (int jj = 0; jj < 8; ++jj) Vt[(d0 + jj) * 72 + t] = u.e[jj];
    }
    __syncthreads();

    // scores = (Q/8) . K^T
    f32x4 sa[2][4];
    #pragma unroll
    for (int i = 0; i < 2; ++i)
      #pragma unroll
      for (int nt = 0; nt < 4; ++nt) sa[i][nt] = (f32x4){0.f, 0.f, 0.f, 0.f};
    #pragma unroll
    for (int kk = 0; kk < 2; ++kk) {
      s16x8 bfr[4];
      #pragma unroll
      for (int nt = 0; nt < 4; ++nt)
        bfr[nt] = *(const s16x8*)&Ks[(nt * 16 + ln) * 64 + kk * 32 + quad * 8];
      #pragma unroll
      for (int i = 0; i < 2; ++i)
        #pragma unroll
        for (int nt = 0; nt < 4; ++nt)
          sa[i][nt] = __builtin_amdgcn_mfma_f32_16x16x32_bf16(qf[i][kk], bfr[nt], sa[i][nt], 0, 0, 0);
    }

    // + bias, online softmax (C layout: row = quad*4+r, col = nt*16+ln)
    #pragma unroll
    for (int i = 0; i < 2; ++i) {
      #pragma unroll
      for (int r = 0; r < 4; ++r) {
        const float* bp = bias + (long)(q0 + w * 32 + i * 16 + quad * 4 + r) * S_LEN + t0 + ln;
        float mx = -3.0e38f;
        #pragma unroll
        for (int nt = 0; nt < 4; ++nt) {
          float sc = sa[i][nt][r] + bp[nt * 16];
          sa[i][nt][r] = sc;
          mx = fmaxf(mx, sc);
        }
        #pragma unroll
        for (int msk = 1; msk < 16; msk <<= 1) mx = fmaxf(mx, __shfl_xor(mx, msk));
        float mold = m_st[i][r];
        float mn = fmaxf(mold, mx);
        float al = exp2f((mold - mn) * LOG2E);
        m_st[i][r] = mn;
        float rs = 0.f;
        #pragma unroll
        for (int nt = 0; nt < 4; ++nt) {
          float p = exp2f((sa[i][nt][r] - mn) * LOG2E);
          rs += p;
          Ps[(w * 32 + i * 16 + quad * 4 + r) * 72 + nt * 16 + ln] = f2bf(p);
        }
        #pragma unroll
        for (int msk = 1; msk < 16; msk <<= 1) rs += __shfl_xor(rs, msk);
        l_st[i][r] = l_st[i][r] * al + rs;
        #pragma unroll
        for (int nt = 0; nt < 4; ++nt) o[i][nt][r] *= al;
      }
    }

    // O += P . V   (P rows are wave-private; same-wave LDS ops are in-order)
    #pragma unroll
    for (int kk = 0; kk < 2; ++kk) {
      s16x8 pa[2], vb[4];
      #pragma unroll
      for (int i = 0; i < 2; ++i)
        pa[i] = *(const s16x8*)&Ps[(w * 32 + i * 16 + ln) * 72 + kk * 32 + quad * 8];
      #pragma unroll
      for (int nt = 0; nt < 4; ++nt)
        vb[nt] = *(const s16x8*)&Vt[(nt * 16 + ln) * 72 + kk * 32 + quad * 8];
      #pragma unroll
      for (int i = 0; i < 2; ++i)
        #pragma unroll
        for (int nt = 0; nt < 4; ++nt)
          o[i][nt] = __builtin_amdgcn_mfma_f32_16x16x32_bf16(pa[i], vb[nt], o[i][nt], 0, 0, 0);
    }
  }

  // epilogue: O / l -> concat (b*S+s, h*64+d) bf16
  #pragma unroll
  for (int i = 0; i < 2; ++i) {
    float inv[4];
    #pragma unroll
    for (int r = 0; r < 4; ++r) inv[r] = 1.0f / l_st[i][r];
    long rowb = (long)bb * S_LEN + q0 + w * 32 + i * 16 + quad * 4;
    #pragma unroll
    for (int nt = 0; nt < 4; ++nt)
      #pragma unroll
      for (int r = 0; r < 4; ++r)
        concat[(rowb + r) * 1024 + h * 64 + nt * 16 + ln] = f2bf(o[i][nt][r] * inv[r]);
  }
}

// ---------------------------------------------------------------------------
// Output GEMM: out[row, n] = sum_k concat[row, k] * WoT[n, k] + bo[n], fp32 out
// ---------------------------------------------------------------------------
__global__ __launch_bounds__(256, 3) void out_gemm(
    const short* __restrict__ A, const short* __restrict__ Bt,
    const float* __restrict__ bo, float* __restrict__ Cout) {
  __shared__ short Asub[128 * 64];
  __shared__ short Bsub[128 * 64];
  const int tid = threadIdx.x;
  const int w = tid >> 6, lane = tid & 63, ln = lane & 15, quad = lane >> 4;
  const int row0 = blockIdx.x * 128, n0 = blockIdx.y * 128;
  const int wm = (w & 1) * 64, wn = (w >> 1) * 64;

  f32x4 acc[4][4];
  #pragma unroll
  for (int i = 0; i < 4; ++i)
    #pragma unroll
    for (int j = 0; j < 4; ++j) acc[i][j] = (f32x4){0.f, 0.f, 0.f, 0.f};

  for (int kt = 0; kt < 16; ++kt) {
    const int k0 = kt * 64;
    #pragma unroll
    for (int j = 0; j < 4; ++j) {
      int chunk = (w * 4 + j) * 64 + lane;
      int r = chunk >> 3, c = chunk & 7;
      const short* ga = A + (long)(row0 + r) * 1024 + k0 + c * 8;
      __builtin_amdgcn_global_load_lds(GA(ga), LA(&Asub[(w * 4 + j) * 512]), 16, 0, 0);
      const short* gb = Bt + (long)(n0 + r) * 1024 + k0 + c * 8;
      __builtin_amdgcn_global_load_lds(GA(gb), LA(&Bsub[(w * 4 + j) * 512]), 16, 0, 0);
    }
    __syncthreads();
    #pragma unroll
    for (int kk = 0; kk < 2; ++kk) {
      s16x8 af[4], bfr[4];
      #pragma unroll
      for (int i = 0; i < 4; ++i)
        af[i] = *(const s16x8*)&Asub[(wm + i * 16 + ln) * 64 + kk * 32 + quad * 8];
      #pragma unroll
      for (int j = 0; j < 4; ++j)
        bfr[j] = *(const s16x8*)&Bsub[(wn + j * 16 + ln) * 64 + kk * 32 + quad * 8];
      #pragma unroll
      for (int i = 0; i < 4; ++i)
        #pragma unroll
        for (int j = 0; j < 4; ++j)
          acc[i][j] = __builtin_amdgcn_mfma_f32_16x16x32_bf16(af[i], bfr[j], acc[i][j], 0, 0, 0);
    }
    __syncthreads();
  }
  #pragma unroll
  for (int j = 0; j < 4; ++j) {
    int n = n0 + wn + j * 16 + ln;
    float bvj = bo[n];
    #pragma unroll
    for (int i = 0; i < 4; ++i) {
      #pragma unroll
      for (int r = 0; r < 4; ++r) {
        int row = row0 + wm + i * 16 + quad * 4 + r;
        Cout[(long)row * 1024 + n] = acc[i][j][r] + bvj;
      }
    }
  }
}

// ---------------------------------------------------------------------------
extern "C" void kernel_launch(void* const* d_in, const int* in_sizes, int n_in,
                              void* d_out, int out_size, void* d_ws, size_t ws_size,
                              hipStream_t stream) {
  const float* query = (const float*)d_in[0];
  const float* key_  = (const float*)d_in[1];
  const float* value = (const float*)d_in[2];
  const float* abias = (const float*)d_in[3];
  const float* Wq = (const float*)d_in[4];
  const float* bq = (const float*)d_in[5];
  const float* Wk = (const float*)d_in[6];
  const float* bk = (const float*)d_in[7];
  const float* Wv = (const float*)d_in[8];
  const float* bv = (const float*)d_in[9];
  const float* Wo = (const float*)d_in[10];
  const float* bo = (const float*)d_in[11];
  float* out = (float*)d_out;

  char* ws = (char*)d_ws;
  short* WqkvT  = (short*)(ws);                 // 3072x1024 bf16  (6 MB)
  short* WoT    = (short*)(ws + 6291456);       // 1024x1024 bf16  (2 MB)
  short* qkv    = (short*)(ws + 8388608);       // 8192x3072 bf16  (48 MB)
  short* concat = (short*)(ws + 58720256);      // 8192x1024 bf16  (16 MB)

  dim3 tb(32, 8);
  transpose_cast<<<dim3(2, 32, 16), tb, 0, stream>>>(Wq, WqkvT,           1024, 64, 65536L, 65536L);
  transpose_cast<<<dim3(2, 32, 16), tb, 0, stream>>>(Wk, WqkvT + 1048576, 1024, 64, 65536L, 65536L);
  transpose_cast<<<dim3(2, 32, 16), tb, 0, stream>>>(Wv, WqkvT + 2097152, 1024, 64, 65536L, 65536L);
  transpose_cast<<<dim3(32, 32, 1), tb, 0, stream>>>(Wo, WoT,             1024, 1024, 0L, 0L);
  proj_gemm<<<dim3(64, 24), 256, 0, stream>>>(query, key_, value, WqkvT, bq, bk, bv, qkv);
  flash_attn<<<dim3(16, 16, 4), 256, 0, stream>>>(qkv, abias, concat);
  out_gemm<<<dim3(64, 8), 256, 0, stream>>>(concat, WoT, bo, out);
}

// Round 2
// 540.317 us; speedup vs baseline: 1.5367x; 1.5367x over previous
//
#include <hip/hip_runtime.h>

#define S_LEN 2048
#define E_DIM 1024
#define H_NUM 16

typedef __attribute__((ext_vector_type(8))) short s16x8;
typedef __attribute__((ext_vector_type(4))) float f32x4;

#define GA(p) ((__attribute__((address_space(1))) void*)(p))
#define LA(p) ((__attribute__((address_space(3))) void*)(p))

#define LOG2E 1.4426950408889634f
#define SCALE_Q (0.125f * LOG2E)

union cvt16 { int4 v; s16x8 s8; short e[8]; };

__device__ __forceinline__ short f2bf(float f) {  // RNE
  union { float f; unsigned u; } v; v.f = f;
  unsigned r = v.u + 0x7FFFu + ((v.u >> 16) & 1u);
  return (short)(r >> 16);
}
__device__ __forceinline__ short f2bf_fast(float f) {  // round-half-up (P in [0,1])
  union { float f; unsigned u; } v; v.f = f;
  return (short)((v.u + 0x8000u) >> 16);
}

// ---------------------------------------------------------------------------
// Transpose + cast + scale: src fp32 (R x C) -> dst bf16 (C x R), batched.
// ---------------------------------------------------------------------------
__global__ void transpose_cast(const float* __restrict__ src, short* __restrict__ dst,
                               int R, int C, long sbs, long dbs, float scale) {
  __shared__ float tile[32][33];
  const float* s = src + (long)blockIdx.z * sbs;
  short* d = dst + (long)blockIdx.z * dbs;
  int c0 = blockIdx.x * 32, r0 = blockIdx.y * 32;
  #pragma unroll
  for (int i = threadIdx.y; i < 32; i += 8)
    tile[i][threadIdx.x] = s[(long)(r0 + i) * C + c0 + threadIdx.x];
  __syncthreads();
  #pragma unroll
  for (int i = threadIdx.y; i < 32; i += 8)
    d[(long)(c0 + i) * R + r0 + threadIdx.x] = f2bf(tile[threadIdx.x][i] * scale);
}

// ---------------------------------------------------------------------------
// Fused QKV projection GEMM. A: fp32 (8192 x 1024) per segment, Bt: bf16
// (3072 x 1024). Segs 0/1 (q,k) -> qk (8192 x 2048) bf16; seg 2 (v) -> VT
// [(b*16+h)*64+d][t] bf16 (transposed for flash V staging). Wq/bq carry
// the log2e/8 score scale (Wq via transpose_cast scale, bq here).
// ---------------------------------------------------------------------------
__global__ __launch_bounds__(256, 3) void proj_gemm(
    const float* __restrict__ Aq, const float* __restrict__ Ak, const float* __restrict__ Av,
    const short* __restrict__ Bt,
    const float* __restrict__ bq, const float* __restrict__ bk, const float* __restrict__ bv,
    short* __restrict__ qkOut, short* __restrict__ VT) {
  __shared__ short Asub[128 * 64];
  __shared__ short Bsub[128 * 64];
  const int tid = threadIdx.x;
  const int w = tid >> 6, lane = tid & 63, ln = lane & 15, quad = lane >> 4;
  const int row0 = blockIdx.x * 128, n0 = blockIdx.y * 128;
  const int seg = n0 >> 10;
  const float* A = (seg == 0) ? Aq : ((seg == 1) ? Ak : Av);
  const float* bptr = (seg == 0) ? bq : ((seg == 1) ? bk : bv);
  const float bscale = (seg == 0) ? SCALE_Q : 1.0f;
  const int nloc = n0 & 1023;
  const int wm = (w & 1) * 64, wn = (w >> 1) * 64;

  f32x4 acc[4][4];
  #pragma unroll
  for (int i = 0; i < 4; ++i)
    #pragma unroll
    for (int j = 0; j < 4; ++j) acc[i][j] = (f32x4){0.f, 0.f, 0.f, 0.f};

  for (int kt = 0; kt < 16; ++kt) {
    const int k0 = kt * 64;
    #pragma unroll
    for (int j = 0; j < 4; ++j) {
      int chunk = (w * 4 + j) * 64 + lane;
      int r = chunk >> 3, c = chunk & 7;
      const short* g = Bt + (long)(n0 + r) * 1024 + k0 + c * 8;
      __builtin_amdgcn_global_load_lds(GA(g), LA(&Bsub[(w * 4 + j) * 512]), 16, 0, 0);
    }
    #pragma unroll
    for (int it = 0; it < 4; ++it) {
      int flat = (it * 256 + tid) * 8;
      int r = flat >> 6, c = flat & 63;
      const float* ga = A + (long)(row0 + r) * 1024 + k0 + c;
      float4 f0 = ((const float4*)ga)[0];
      float4 f1 = ((const float4*)ga)[1];
      s16x8 s8;
      s8[0] = f2bf(f0.x); s8[1] = f2bf(f0.y); s8[2] = f2bf(f0.z); s8[3] = f2bf(f0.w);
      s8[4] = f2bf(f1.x); s8[5] = f2bf(f1.y); s8[6] = f2bf(f1.z); s8[7] = f2bf(f1.w);
      *(s16x8*)&Asub[r * 64 + c] = s8;
    }
    __syncthreads();
    #pragma unroll
    for (int kk = 0; kk < 2; ++kk) {
      s16x8 af[4], bfr[4];
      #pragma unroll
      for (int i = 0; i < 4; ++i)
        af[i] = *(const s16x8*)&Asub[(wm + i * 16 + ln) * 64 + kk * 32 + quad * 8];
      #pragma unroll
      for (int j = 0; j < 4; ++j)
        bfr[j] = *(const s16x8*)&Bsub[(wn + j * 16 + ln) * 64 + kk * 32 + quad * 8];
      #pragma unroll
      for (int i = 0; i < 4; ++i)
        #pragma unroll
        for (int j = 0; j < 4; ++j)
          acc[i][j] = __builtin_amdgcn_mfma_f32_16x16x32_bf16(af[i], bfr[j], acc[i][j], 0, 0, 0);
    }
    __syncthreads();
  }
  if (seg < 2) {
    #pragma unroll
    for (int j = 0; j < 4; ++j) {
      float bvj = bptr[nloc + wn + j * 16 + ln] * bscale;
      int n = n0 + wn + j * 16 + ln;
      #pragma unroll
      for (int i = 0; i < 4; ++i) {
        #pragma unroll
        for (int r = 0; r < 4; ++r) {
          int row = row0 + wm + i * 16 + quad * 4 + r;
          qkOut[(long)row * 2048 + n] = f2bf(acc[i][j][r] + bvj);
        }
      }
    }
  } else {
    #pragma unroll
    for (int j = 0; j < 4; ++j) {
      int nl = nloc + wn + j * 16 + ln;
      int hh = nl >> 6, d = nl & 63;
      float bvj = bptr[nl];
      #pragma unroll
      for (int i = 0; i < 4; ++i) {
        int row = row0 + wm + i * 16 + quad * 4;
        int b = row >> 11, t = row & 2047;
        short4 sv;
        sv.x = f2bf(acc[i][j][0] + bvj);
        sv.y = f2bf(acc[i][j][1] + bvj);
        sv.z = f2bf(acc[i][j][2] + bvj);
        sv.w = f2bf(acc[i][j][3] + bvj);
        *(short4*)&VT[((long)(b * 16 + hh) * 64 + d) * 2048 + t] = sv;
      }
    }
  }
}

// ---------------------------------------------------------------------------
// Flash attention, double-buffered DMA staging, XOR-swizzled LDS.
// Grid (S/128, H, B), block 256 (4 waves x 32 q-rows).
// qk: bf16 (8192 x 2048) [q | k], VT: bf16 [(b,h,d), t], bias fp32 (2048x2048),
// concat bf16 (8192 x 1024). Scores carry log2e/8 via Wq/bq prep.
// ---------------------------------------------------------------------------
__global__ __launch_bounds__(256, 3) void flash_attn(
    const short* __restrict__ qk, const short* __restrict__ VT,
    const float* __restrict__ bias, short* __restrict__ concat) {
  __shared__ short Ks[2][4096];   // (t, d) xor-swizzled 16B chunks
  __shared__ short Vs[2][4096];   // (d, t) xor-swizzled 16B chunks
  __shared__ short Ps[128 * 72];  // (qrow, t) pad 72
  const int tid = threadIdx.x;
  const int w = tid >> 6, lane = tid & 63, ln = lane & 15, quad = lane >> 4;
  const int q0 = blockIdx.x * 128;
  const int h = blockIdx.y, bb = blockIdx.z;

  // Q fragments in registers (already scaled by log2e/8 at prep)
  s16x8 qf[2][2];
  const short* qbase = qk + (long)(bb * 2048 + q0 + w * 32) * 2048 + h * 64;
  #pragma unroll
  for (int i = 0; i < 2; ++i)
    #pragma unroll
    for (int kk = 0; kk < 2; ++kk) {
      cvt16 u; u.v = *(const int4*)(qbase + (long)(i * 16 + ln) * 2048 + kk * 32 + quad * 8);
      qf[i][kk] = u.s8;
    }

  f32x4 o[2][4];
  float m_st[2][4], l_st[2][4];
  #pragma unroll
  for (int i = 0; i < 2; ++i) {
    #pragma unroll
    for (int nt = 0; nt < 4; ++nt) o[i][nt] = (f32x4){0.f, 0.f, 0.f, 0.f};
    #pragma unroll
    for (int r = 0; r < 4; ++r) { m_st[i][r] = -3.0e38f; l_st[i][r] = 0.f; }
  }

  const short* kbase = qk + (long)bb * 2048 * 2048 + 1024 + h * 64;
  const short* vbase = VT + (long)(bb * 16 + h) * 64 * 2048;
  const float* bbase = bias + (long)(q0 + w * 32 + quad * 4) * 2048 + ln;

  // stage kv=0 into buffer 0
  #pragma unroll
  for (int j = 0; j < 2; ++j) {
    int ci = (w * 2 + j) * 64 + lane;
    int r = ci >> 3, cs = (ci & 7) ^ (r & 7);
    __builtin_amdgcn_global_load_lds(GA(kbase + (long)r * 2048 + cs * 8), LA(&Ks[0][(w * 2 + j) * 512]), 16, 0, 0);
    __builtin_amdgcn_global_load_lds(GA(vbase + (long)r * 2048 + cs * 8), LA(&Vs[0][(w * 2 + j) * 512]), 16, 0, 0);
  }

  for (int kv = 0; kv < 32; ++kv) {
    const int t0 = kv * 64, b = kv & 1;
    __syncthreads();  // own DMA drained pre-barrier -> buf b ready, buf b^1 free

    // bias loads for THIS iter: issued before next DMA so their wait is vmcnt(4)
    float bld[2][4][4];
    #pragma unroll
    for (int i = 0; i < 2; ++i)
      #pragma unroll
      for (int r = 0; r < 4; ++r) {
        const float* bp = bbase + (long)(i * 16 + r) * 2048 + t0;
        #pragma unroll
        for (int nt = 0; nt < 4; ++nt) bld[i][nt][r] = bp[nt * 16];
      }
    __builtin_amdgcn_sched_barrier(0);  // keep bias loads older than the DMAs

    if (kv < 31) {  // prefetch kv+1 into other buffer (overlaps this compute)
      const short* kb = kbase + (long)(t0 + 64) * 2048;
      const short* vb = vbase + (t0 + 64);
      #pragma unroll
      for (int j = 0; j < 2; ++j) {
        int ci = (w * 2 + j) * 64 + lane;
        int r = ci >> 3, cs = (ci & 7) ^ (r & 7);
        __builtin_amdgcn_global_load_lds(GA(kb + (long)r * 2048 + cs * 8), LA(&Ks[b ^ 1][(w * 2 + j) * 512]), 16, 0, 0);
        __builtin_amdgcn_global_load_lds(GA(vb + (long)r * 2048 + cs * 8), LA(&Vs[b ^ 1][(w * 2 + j) * 512]), 16, 0, 0);
      }
    }

    // scores (log2-domain): sa = (log2e/8) * Q.K^T
    f32x4 sa[2][4];
    #pragma unroll
    for (int i = 0; i < 2; ++i)
      #pragma unroll
      for (int nt = 0; nt < 4; ++nt) sa[i][nt] = (f32x4){0.f, 0.f, 0.f, 0.f};
    #pragma unroll
    for (int kk = 0; kk < 2; ++kk) {
      s16x8 bfr[4];
      #pragma unroll
      for (int nt = 0; nt < 4; ++nt)
        bfr[nt] = *(const s16x8*)&Ks[b][((nt * 16 + ln) << 6) + (((kk * 4 + quad) ^ (ln & 7)) << 3)];
      #pragma unroll
      for (int i = 0; i < 2; ++i)
        #pragma unroll
        for (int nt = 0; nt < 4; ++nt)
          sa[i][nt] = __builtin_amdgcn_mfma_f32_16x16x32_bf16(qf[i][kk], bfr[nt], sa[i][nt], 0, 0, 0);
    }

    // + bias*log2e, online softmax in exp2 domain
    #pragma unroll
    for (int i = 0; i < 2; ++i) {
      #pragma unroll
      for (int r = 0; r < 4; ++r) {
        float sc[4];
        float mx = -3.0e38f;
        #pragma unroll
        for (int nt = 0; nt < 4; ++nt) {
          sc[nt] = fmaf(bld[i][nt][r], LOG2E, sa[i][nt][r]);
          mx = fmaxf(mx, sc[nt]);
        }
        #pragma unroll
        for (int msk = 1; msk < 16; msk <<= 1) mx = fmaxf(mx, __shfl_xor(mx, msk));
        float mold = m_st[i][r];
        float mn = fmaxf(mold, mx);
        float al = exp2f(mold - mn);
        m_st[i][r] = mn;
        float rs = 0.f;
        #pragma unroll
        for (int nt = 0; nt < 4; ++nt) {
          float p = exp2f(sc[nt] - mn);
          rs += p;
          Ps[(w * 32 + i * 16 + quad * 4 + r) * 72 + nt * 16 + ln] = f2bf_fast(p);
        }
        #pragma unroll
        for (int msk = 1; msk < 16; msk <<= 1) rs += __shfl_xor(rs, msk);
        l_st[i][r] = l_st[i][r] * al + rs;
        #pragma unroll
        for (int nt = 0; nt < 4; ++nt) o[i][nt][r] *= al;
      }
    }

    // O += P . V  (Ps rows wave-private; same-wave LDS ordering suffices)
    #pragma unroll
    for (int kk = 0; kk < 2; ++kk) {
      s16x8 pa[2], vbf[4];
      #pragma unroll
      for (int i = 0; i < 2; ++i)
        pa[i] = *(const s16x8*)&Ps[(w * 32 + i * 16 + ln) * 72 + kk * 32 + quad * 8];
      #pragma unroll
      for (int nt = 0; nt < 4; ++nt)
        vbf[nt] = *(const s16x8*)&Vs[b][((nt * 16 + ln) << 6) + (((kk * 4 + quad) ^ (ln & 7)) << 3)];
      #pragma unroll
      for (int i = 0; i < 2; ++i)
        #pragma unroll
        for (int nt = 0; nt < 4; ++nt)
          o[i][nt] = __builtin_amdgcn_mfma_f32_16x16x32_bf16(pa[i], vbf[nt], o[i][nt], 0, 0, 0);
    }
  }

  // epilogue: O / l -> concat
  #pragma unroll
  for (int i = 0; i < 2; ++i) {
    float inv[4];
    #pragma unroll
    for (int r = 0; r < 4; ++r) inv[r] = 1.0f / l_st[i][r];
    long rowb = (long)bb * 2048 + q0 + w * 32 + i * 16 + quad * 4;
    #pragma unroll
    for (int nt = 0; nt < 4; ++nt)
      #pragma unroll
      for (int r = 0; r < 4; ++r)
        concat[(rowb + r) * 1024 + h * 64 + nt * 16 + ln] = f2bf(o[i][nt][r] * inv[r]);
  }
}

// ---------------------------------------------------------------------------
// Output GEMM: out[row, n] = sum_k concat[row, k] * WoT[n, k] + bo[n], fp32 out
// ---------------------------------------------------------------------------
__global__ __launch_bounds__(256, 3) void out_gemm(
    const short* __restrict__ A, const short* __restrict__ Bt,
    const float* __restrict__ bo, float* __restrict__ Cout) {
  __shared__ short Asub[128 * 64];
  __shared__ short Bsub[128 * 64];
  const int tid = threadIdx.x;
  const int w = tid >> 6, lane = tid & 63, ln = lane & 15, quad = lane >> 4;
  const int row0 = blockIdx.x * 128, n0 = blockIdx.y * 128;
  const int wm = (w & 1) * 64, wn = (w >> 1) * 64;

  f32x4 acc[4][4];
  #pragma unroll
  for (int i = 0; i < 4; ++i)
    #pragma unroll
    for (int j = 0; j < 4; ++j) acc[i][j] = (f32x4){0.f, 0.f, 0.f, 0.f};

  for (int kt = 0; kt < 16; ++kt) {
    const int k0 = kt * 64;
    #pragma unroll
    for (int j = 0; j < 4; ++j) {
      int chunk = (w * 4 + j) * 64 + lane;
      int r = chunk >> 3, c = chunk & 7;
      const short* ga = A + (long)(row0 + r) * 1024 + k0 + c * 8;
      __builtin_amdgcn_global_load_lds(GA(ga), LA(&Asub[(w * 4 + j) * 512]), 16, 0, 0);
      const short* gb = Bt + (long)(n0 + r) * 1024 + k0 + c * 8;
      __builtin_amdgcn_global_load_lds(GA(gb), LA(&Bsub[(w * 4 + j) * 512]), 16, 0, 0);
    }
    __syncthreads();
    #pragma unroll
    for (int kk = 0; kk < 2; ++kk) {
      s16x8 af[4], bfr[4];
      #pragma unroll
      for (int i = 0; i < 4; ++i)
        af[i] = *(const s16x8*)&Asub[(wm + i * 16 + ln) * 64 + kk * 32 + quad * 8];
      #pragma unroll
      for (int j = 0; j < 4; ++j)
        bfr[j] = *(const s16x8*)&Bsub[(wn + j * 16 + ln) * 64 + kk * 32 + quad * 8];
      #pragma unroll
      for (int i = 0; i < 4; ++i)
        #pragma unroll
        for (int j = 0; j < 4; ++j)
          acc[i][j] = __builtin_amdgcn_mfma_f32_16x16x32_bf16(af[i], bfr[j], acc[i][j], 0, 0, 0);
    }
    __syncthreads();
  }
  #pragma unroll
  for (int j = 0; j < 4; ++j) {
    int n = n0 + wn + j * 16 + ln;
    float bvj = bo[n];
    #pragma unroll
    for (int i = 0; i < 4; ++i) {
      #pragma unroll
      for (int r = 0; r < 4; ++r) {
        int row = row0 + wm + i * 16 + quad * 4 + r;
        Cout[(long)row * 1024 + n] = acc[i][j][r] + bvj;
      }
    }
  }
}

// ---------------------------------------------------------------------------
extern "C" void kernel_launch(void* const* d_in, const int* in_sizes, int n_in,
                              void* d_out, int out_size, void* d_ws, size_t ws_size,
                              hipStream_t stream) {
  const float* query = (const float*)d_in[0];
  const float* key_  = (const float*)d_in[1];
  const float* value = (const float*)d_in[2];
  const float* abias = (const float*)d_in[3];
  const float* Wq = (const float*)d_in[4];
  const float* bq = (const float*)d_in[5];
  const float* Wk = (const float*)d_in[6];
  const float* bk = (const float*)d_in[7];
  const float* Wv = (const float*)d_in[8];
  const float* bv = (const float*)d_in[9];
  const float* Wo = (const float*)d_in[10];
  const float* bo = (const float*)d_in[11];
  float* out = (float*)d_out;

  char* ws = (char*)d_ws;
  short* WqkvT  = (short*)(ws);                 // 3072x1024 bf16  (6 MB)
  short* WoT    = (short*)(ws + 6291456);       // 1024x1024 bf16  (2 MB)
  short* qk     = (short*)(ws + 8388608);       // 8192x2048 bf16  (32 MB)
  short* VT     = (short*)(ws + 41943040);      // 64bh x 64d x 2048t bf16 (16 MB)
  short* concat = (short*)(ws + 58720256);      // 8192x1024 bf16  (16 MB)

  dim3 tb(32, 8);
  transpose_cast<<<dim3(2, 32, 16), tb, 0, stream>>>(Wq, WqkvT,           1024, 64, 65536L, 65536L, SCALE_Q);
  transpose_cast<<<dim3(2, 32, 16), tb, 0, stream>>>(Wk, WqkvT + 1048576, 1024, 64, 65536L, 65536L, 1.0f);
  transpose_cast<<<dim3(2, 32, 16), tb, 0, stream>>>(Wv, WqkvT + 2097152, 1024, 64, 65536L, 65536L, 1.0f);
  transpose_cast<<<dim3(32, 32, 1), tb, 0, stream>>>(Wo, WoT,             1024, 1024, 0L, 0L, 1.0f);
  proj_gemm<<<dim3(64, 24), 256, 0, stream>>>(query, key_, value, WqkvT, bq, bk, bv, qk, VT);
  flash_attn<<<dim3(16, 16, 4), 256, 0, stream>>>(qk, VT, abias, concat);
  out_gemm<<<dim3(64, 8), 256, 0, stream>>>(concat, WoT, bo, out);
}

// Round 3
// 422.336 us; speedup vs baseline: 1.9660x; 1.2794x over previous
//
#include <hip/hip_runtime.h>

#define S_LEN 2048
#define E_DIM 1024
#define H_NUM 16

typedef __attribute__((ext_vector_type(8))) short s16x8;
typedef __attribute__((ext_vector_type(4))) float f32x4;

#define GA(p) ((__attribute__((address_space(1))) void*)(p))
#define LA(p) ((__attribute__((address_space(3))) void*)(p))

#define LOG2E 1.4426950408889634f
#define SCALE_Q (0.125f * LOG2E)
#define SHIFT 12.0f   // folded into QK accumulator init; cancels in p/l

union cvt16 { int4 v; s16x8 s8; short e[8]; };

__device__ __forceinline__ short f2bf(float f) {  // RNE
  union { float f; unsigned u; } v; v.f = f;
  unsigned r = v.u + 0x7FFFu + ((v.u >> 16) & 1u);
  return (short)(r >> 16);
}
__device__ __forceinline__ short f2bf_fast(float f) {  // round-half-up (p >= 0)
  union { float f; unsigned u; } v; v.f = f;
  return (short)((v.u + 0x8000u) >> 16);
}

// ---------------------------------------------------------------------------
// Transpose + cast + scale: src fp32 (R x C) -> dst bf16 (C x R), batched.
// ---------------------------------------------------------------------------
__global__ void transpose_cast(const float* __restrict__ src, short* __restrict__ dst,
                               int R, int C, long sbs, long dbs, float scale) {
  __shared__ float tile[32][33];
  const float* s = src + (long)blockIdx.z * sbs;
  short* d = dst + (long)blockIdx.z * dbs;
  int c0 = blockIdx.x * 32, r0 = blockIdx.y * 32;
  #pragma unroll
  for (int i = threadIdx.y; i < 32; i += 8)
    tile[i][threadIdx.x] = s[(long)(r0 + i) * C + c0 + threadIdx.x];
  __syncthreads();
  #pragma unroll
  for (int i = threadIdx.y; i < 32; i += 8)
    d[(long)(c0 + i) * R + r0 + threadIdx.x] = f2bf(tile[threadIdx.x][i] * scale);
}

// ---------------------------------------------------------------------------
// Elementwise fp32 -> bf16 cast of q,k,v (z selects array). 4 elems/thread.
// ---------------------------------------------------------------------------
__global__ void cast3_bf16(const float* __restrict__ q, const float* __restrict__ k,
                           const float* __restrict__ v, short* __restrict__ dst) {
  const float* s = (blockIdx.z == 0) ? q : ((blockIdx.z == 1) ? k : v);
  short* d = dst + (long)blockIdx.z * 8388608;
  long i = ((long)blockIdx.x * 256 + threadIdx.x) * 4;
  float4 f = *(const float4*)(s + i);
  short4 o;
  o.x = f2bf(f.x); o.y = f2bf(f.y); o.z = f2bf(f.z); o.w = f2bf(f.w);
  *(short4*)(d + i) = o;
}

// ---------------------------------------------------------------------------
// QKV projection GEMM, bf16-A fast path (pure global_load_lds staging).
// A: bf16 (8192x1024) per segment, Bt: bf16 (3072x1024).
// Segs 0/1 -> qk (8192x2048); seg 2 -> VT [(b*16+h)*64+d][t].
// ---------------------------------------------------------------------------
__global__ __launch_bounds__(256, 3) void proj_gemm_bf(
    const short* __restrict__ Aq, const short* __restrict__ Ak, const short* __restrict__ Av,
    const short* __restrict__ Bt,
    const float* __restrict__ bq, const float* __restrict__ bk, const float* __restrict__ bv,
    short* __restrict__ qkOut, short* __restrict__ VT) {
  __shared__ short Asub[128 * 64];
  __shared__ short Bsub[128 * 64];
  const int tid = threadIdx.x;
  const int w = tid >> 6, lane = tid & 63, ln = lane & 15, quad = lane >> 4;
  const int row0 = blockIdx.x * 128, n0 = blockIdx.y * 128;
  const int seg = n0 >> 10;
  const short* A = (seg == 0) ? Aq : ((seg == 1) ? Ak : Av);
  const float* bptr = (seg == 0) ? bq : ((seg == 1) ? bk : bv);
  const float bscale = (seg == 0) ? SCALE_Q : 1.0f;
  const int nloc = n0 & 1023;
  const int wm = (w & 1) * 64, wn = (w >> 1) * 64;

  f32x4 acc[4][4];
  #pragma unroll
  for (int i = 0; i < 4; ++i)
    #pragma unroll
    for (int j = 0; j < 4; ++j) acc[i][j] = (f32x4){0.f, 0.f, 0.f, 0.f};

  for (int kt = 0; kt < 16; ++kt) {
    const int k0 = kt * 64;
    #pragma unroll
    for (int j = 0; j < 4; ++j) {
      int chunk = (w * 4 + j) * 64 + lane;
      int r = chunk >> 3, c = chunk & 7;
      const short* ga = A + (long)(row0 + r) * 1024 + k0 + c * 8;
      __builtin_amdgcn_global_load_lds(GA(ga), LA(&Asub[(w * 4 + j) * 512]), 16, 0, 0);
      const short* gb = Bt + (long)(n0 + r) * 1024 + k0 + c * 8;
      __builtin_amdgcn_global_load_lds(GA(gb), LA(&Bsub[(w * 4 + j) * 512]), 16, 0, 0);
    }
    __syncthreads();
    #pragma unroll
    for (int kk = 0; kk < 2; ++kk) {
      s16x8 af[4], bfr[4];
      #pragma unroll
      for (int i = 0; i < 4; ++i)
        af[i] = *(const s16x8*)&Asub[(wm + i * 16 + ln) * 64 + kk * 32 + quad * 8];
      #pragma unroll
      for (int j = 0; j < 4; ++j)
        bfr[j] = *(const s16x8*)&Bsub[(wn + j * 16 + ln) * 64 + kk * 32 + quad * 8];
      #pragma unroll
      for (int i = 0; i < 4; ++i)
        #pragma unroll
        for (int j = 0; j < 4; ++j)
          acc[i][j] = __builtin_amdgcn_mfma_f32_16x16x32_bf16(af[i], bfr[j], acc[i][j], 0, 0, 0);
    }
    __syncthreads();
  }
  if (seg < 2) {
    #pragma unroll
    for (int j = 0; j < 4; ++j) {
      float bvj = bptr[nloc + wn + j * 16 + ln] * bscale;
      int n = n0 + wn + j * 16 + ln;
      #pragma unroll
      for (int i = 0; i < 4; ++i)
        #pragma unroll
        for (int r = 0; r < 4; ++r) {
          int row = row0 + wm + i * 16 + quad * 4 + r;
          qkOut[(long)row * 2048 + n] = f2bf(acc[i][j][r] + bvj);
        }
    }
  } else {
    #pragma unroll
    for (int j = 0; j < 4; ++j) {
      int nl = nloc + wn + j * 16 + ln;
      int hh = nl >> 6, d = nl & 63;
      float bvj = bptr[nl];
      #pragma unroll
      for (int i = 0; i < 4; ++i) {
        int row = row0 + wm + i * 16 + quad * 4;
        int b = row >> 11, t = row & 2047;
        short4 sv;
        sv.x = f2bf(acc[i][j][0] + bvj);
        sv.y = f2bf(acc[i][j][1] + bvj);
        sv.z = f2bf(acc[i][j][2] + bvj);
        sv.w = f2bf(acc[i][j][3] + bvj);
        *(short4*)&VT[((long)(b * 16 + hh) * 64 + d) * 2048 + t] = sv;
      }
    }
  }
}

// ---------------------------------------------------------------------------
// QKV projection GEMM, fp32-A fallback (R2 path; used if ws too small).
// ---------------------------------------------------------------------------
__global__ __launch_bounds__(256, 3) void proj_gemm_f32(
    const float* __restrict__ Aq, const float* __restrict__ Ak, const float* __restrict__ Av,
    const short* __restrict__ Bt,
    const float* __restrict__ bq, const float* __restrict__ bk, const float* __restrict__ bv,
    short* __restrict__ qkOut, short* __restrict__ VT) {
  __shared__ short Asub[128 * 64];
  __shared__ short Bsub[128 * 64];
  const int tid = threadIdx.x;
  const int w = tid >> 6, lane = tid & 63, ln = lane & 15, quad = lane >> 4;
  const int row0 = blockIdx.x * 128, n0 = blockIdx.y * 128;
  const int seg = n0 >> 10;
  const float* A = (seg == 0) ? Aq : ((seg == 1) ? Ak : Av);
  const float* bptr = (seg == 0) ? bq : ((seg == 1) ? bk : bv);
  const float bscale = (seg == 0) ? SCALE_Q : 1.0f;
  const int nloc = n0 & 1023;
  const int wm = (w & 1) * 64, wn = (w >> 1) * 64;

  f32x4 acc[4][4];
  #pragma unroll
  for (int i = 0; i < 4; ++i)
    #pragma unroll
    for (int j = 0; j < 4; ++j) acc[i][j] = (f32x4){0.f, 0.f, 0.f, 0.f};

  for (int kt = 0; kt < 16; ++kt) {
    const int k0 = kt * 64;
    #pragma unroll
    for (int j = 0; j < 4; ++j) {
      int chunk = (w * 4 + j) * 64 + lane;
      int r = chunk >> 3, c = chunk & 7;
      const short* g = Bt + (long)(n0 + r) * 1024 + k0 + c * 8;
      __builtin_amdgcn_global_load_lds(GA(g), LA(&Bsub[(w * 4 + j) * 512]), 16, 0, 0);
    }
    #pragma unroll
    for (int it = 0; it < 4; ++it) {
      int flat = (it * 256 + tid) * 8;
      int r = flat >> 6, c = flat & 63;
      const float* ga = A + (long)(row0 + r) * 1024 + k0 + c;
      float4 f0 = ((const float4*)ga)[0];
      float4 f1 = ((const float4*)ga)[1];
      s16x8 s8;
      s8[0] = f2bf(f0.x); s8[1] = f2bf(f0.y); s8[2] = f2bf(f0.z); s8[3] = f2bf(f0.w);
      s8[4] = f2bf(f1.x); s8[5] = f2bf(f1.y); s8[6] = f2bf(f1.z); s8[7] = f2bf(f1.w);
      *(s16x8*)&Asub[r * 64 + c] = s8;
    }
    __syncthreads();
    #pragma unroll
    for (int kk = 0; kk < 2; ++kk) {
      s16x8 af[4], bfr[4];
      #pragma unroll
      for (int i = 0; i < 4; ++i)
        af[i] = *(const s16x8*)&Asub[(wm + i * 16 + ln) * 64 + kk * 32 + quad * 8];
      #pragma unroll
      for (int j = 0; j < 4; ++j)
        bfr[j] = *(const s16x8*)&Bsub[(wn + j * 16 + ln) * 64 + kk * 32 + quad * 8];
      #pragma unroll
      for (int i = 0; i < 4; ++i)
        #pragma unroll
        for (int j = 0; j < 4; ++j)
          acc[i][j] = __builtin_amdgcn_mfma_f32_16x16x32_bf16(af[i], bfr[j], acc[i][j], 0, 0, 0);
    }
    __syncthreads();
  }
  if (seg < 2) {
    #pragma unroll
    for (int j = 0; j < 4; ++j) {
      float bvj = bptr[nloc + wn + j * 16 + ln] * bscale;
      int n = n0 + wn + j * 16 + ln;
      #pragma unroll
      for (int i = 0; i < 4; ++i)
        #pragma unroll
        for (int r = 0; r < 4; ++r) {
          int row = row0 + wm + i * 16 + quad * 4 + r;
          qkOut[(long)row * 2048 + n] = f2bf(acc[i][j][r] + bvj);
        }
    }
  } else {
    #pragma unroll
    for (int j = 0; j < 4; ++j) {
      int nl = nloc + wn + j * 16 + ln;
      int hh = nl >> 6, d = nl & 63;
      float bvj = bptr[nl];
      #pragma unroll
      for (int i = 0; i < 4; ++i) {
        int row = row0 + wm + i * 16 + quad * 4;
        int b = row >> 11, t = row & 2047;
        short4 sv;
        sv.x = f2bf(acc[i][j][0] + bvj);
        sv.y = f2bf(acc[i][j][1] + bvj);
        sv.z = f2bf(acc[i][j][2] + bvj);
        sv.w = f2bf(acc[i][j][3] + bvj);
        *(short4*)&VT[((long)(b * 16 + hh) * 64 + d) * 2048 + t] = sv;
      }
    }
  }
}

// ---------------------------------------------------------------------------
// Flash attention, shift-softmax (no online max): acc init = -SHIFT, l via
// MFMA ones-trick. Double-buffered DMA, XOR-swizzled LDS. Grid (S/128, H, B).
// ---------------------------------------------------------------------------
__global__ __launch_bounds__(256, 3) void flash_attn(
    const short* __restrict__ qk, const short* __restrict__ VT,
    const float* __restrict__ bias, short* __restrict__ concat) {
  __shared__ short Ks[2][4096];   // (t, d) xor-swizzled 16B chunks
  __shared__ short Vs[2][4096];   // (d, t) xor-swizzled 16B chunks
  __shared__ short Ps[128 * 72];  // (qrow, t) pad 72
  const int tid = threadIdx.x;
  const int w = tid >> 6, lane = tid & 63, ln = lane & 15, quad = lane >> 4;
  const int q0 = blockIdx.x * 128;
  const int h = blockIdx.y, bb = blockIdx.z;

  // bf16 1.0 vector for the l row-sum MFMA
  s16x8 ones;
  #pragma unroll
  for (int e = 0; e < 8; ++e) ones[e] = (short)0x3F80;

  // Q fragments (pre-scaled by log2e/8 at prep)
  s16x8 qf[2][2];
  const short* qbase = qk + (long)(bb * 2048 + q0 + w * 32) * 2048 + h * 64;
  #pragma unroll
  for (int i = 0; i < 2; ++i)
    #pragma unroll
    for (int kk = 0; kk < 2; ++kk) {
      cvt16 u; u.v = *(const int4*)(qbase + (long)(i * 16 + ln) * 2048 + kk * 32 + quad * 8);
      qf[i][kk] = u.s8;
    }

  f32x4 o[2][4], lacc[2];
  #pragma unroll
  for (int i = 0; i < 2; ++i) {
    #pragma unroll
    for (int nt = 0; nt < 4; ++nt) o[i][nt] = (f32x4){0.f, 0.f, 0.f, 0.f};
    lacc[i] = (f32x4){0.f, 0.f, 0.f, 0.f};
  }

  const short* kbase = qk + (long)bb * 2048 * 2048 + 1024 + h * 64;
  const short* vbase = VT + (long)(bb * 16 + h) * 64 * 2048;
  const float* bbase = bias + (long)(q0 + w * 32 + quad * 4) * 2048 + ln;

  // stage kv=0 into buffer 0
  #pragma unroll
  for (int j = 0; j < 2; ++j) {
    int ci = (w * 2 + j) * 64 + lane;
    int r = ci >> 3, cs = (ci & 7) ^ (r & 7);
    __builtin_amdgcn_global_load_lds(GA(kbase + (long)r * 2048 + cs * 8), LA(&Ks[0][(w * 2 + j) * 512]), 16, 0, 0);
    __builtin_amdgcn_global_load_lds(GA(vbase + (long)r * 2048 + cs * 8), LA(&Vs[0][(w * 2 + j) * 512]), 16, 0, 0);
  }

  for (int kv = 0; kv < 32; ++kv) {
    const int t0 = kv * 64, b = kv & 1;
    __syncthreads();  // own DMA drained pre-barrier -> buf b ready, buf b^1 free

    // bias loads for THIS iter, issued before the prefetch DMAs
    float bld[2][4][4];
    #pragma unroll
    for (int i = 0; i < 2; ++i)
      #pragma unroll
      for (int r = 0; r < 4; ++r) {
        const float* bp = bbase + (long)(i * 16 + r) * 2048 + t0;
        #pragma unroll
        for (int nt = 0; nt < 4; ++nt) bld[i][nt][r] = bp[nt * 16];
      }
    __builtin_amdgcn_sched_barrier(0);

    if (kv < 31) {  // prefetch kv+1 into other buffer
      const short* kb = kbase + (long)(t0 + 64) * 2048;
      const short* vb = vbase + (t0 + 64);
      #pragma unroll
      for (int j = 0; j < 2; ++j) {
        int ci = (w * 2 + j) * 64 + lane;
        int r = ci >> 3, cs = (ci & 7) ^ (r & 7);
        __builtin_amdgcn_global_load_lds(GA(kb + (long)r * 2048 + cs * 8), LA(&Ks[b ^ 1][(w * 2 + j) * 512]), 16, 0, 0);
        __builtin_amdgcn_global_load_lds(GA(vb + (long)r * 2048 + cs * 8), LA(&Vs[b ^ 1][(w * 2 + j) * 512]), 16, 0, 0);
      }
    }

    // scores (log2 domain, pre-shifted): sa = -SHIFT + (log2e/8) Q.K^T
    f32x4 sa[2][4];
    #pragma unroll
    for (int i = 0; i < 2; ++i)
      #pragma unroll
      for (int nt = 0; nt < 4; ++nt) sa[i][nt] = (f32x4){-SHIFT, -SHIFT, -SHIFT, -SHIFT};
    #pragma unroll
    for (int kk = 0; kk < 2; ++kk) {
      s16x8 bfr[4];
      #pragma unroll
      for (int nt = 0; nt < 4; ++nt)
        bfr[nt] = *(const s16x8*)&Ks[b][((nt * 16 + ln) << 6) + (((kk * 4 + quad) ^ (ln & 7)) << 3)];
      #pragma unroll
      for (int i = 0; i < 2; ++i)
        #pragma unroll
        for (int nt = 0; nt < 4; ++nt)
          sa[i][nt] = __builtin_amdgcn_mfma_f32_16x16x32_bf16(qf[i][kk], bfr[nt], sa[i][nt], 0, 0, 0);
    }

    // p = 2^(sa + bias*log2e); no max tracking (shift-invariant softmax)
    #pragma unroll
    for (int i = 0; i < 2; ++i)
      #pragma unroll
      for (int r = 0; r < 4; ++r) {
        #pragma unroll
        for (int nt = 0; nt < 4; ++nt) {
          float p = __builtin_amdgcn_exp2f(fmaf(bld[i][nt][r], LOG2E, sa[i][nt][r]));
          Ps[(w * 32 + i * 16 + quad * 4 + r) * 72 + nt * 16 + ln] = f2bf_fast(p);
        }
      }

    // O += P.V ; l += P.1  (Ps rows wave-private; same-wave LDS ordering ok)
    #pragma unroll
    for (int kk = 0; kk < 2; ++kk) {
      s16x8 pa[2], vbf[4];
      #pragma unroll
      for (int i = 0; i < 2; ++i)
        pa[i] = *(const s16x8*)&Ps[(w * 32 + i * 16 + ln) * 72 + kk * 32 + quad * 8];
      #pragma unroll
      for (int nt = 0; nt < 4; ++nt)
        vbf[nt] = *(const s16x8*)&Vs[b][((nt * 16 + ln) << 6) + (((kk * 4 + quad) ^ (ln & 7)) << 3)];
      #pragma unroll
      for (int i = 0; i < 2; ++i) {
        #pragma unroll
        for (int nt = 0; nt < 4; ++nt)
          o[i][nt] = __builtin_amdgcn_mfma_f32_16x16x32_bf16(pa[i], vbf[nt], o[i][nt], 0, 0, 0);
        lacc[i] = __builtin_amdgcn_mfma_f32_16x16x32_bf16(pa[i], ones, lacc[i], 0, 0, 0);
      }
    }
  }

  // epilogue: O / l -> concat
  #pragma unroll
  for (int i = 0; i < 2; ++i) {
    float inv[4];
    #pragma unroll
    for (int r = 0; r < 4; ++r) inv[r] = __builtin_amdgcn_rcpf(lacc[i][r]);
    long rowb = (long)bb * 2048 + q0 + w * 32 + i * 16 + quad * 4;
    #pragma unroll
    for (int nt = 0; nt < 4; ++nt)
      #pragma unroll
      for (int r = 0; r < 4; ++r)
        concat[(rowb + r) * 1024 + h * 64 + nt * 16 + ln] = f2bf(o[i][nt][r] * inv[r]);
  }
}

// ---------------------------------------------------------------------------
// Output GEMM: out[row, n] = sum_k concat[row, k] * WoT[n, k] + bo[n], fp32 out
// ---------------------------------------------------------------------------
__global__ __launch_bounds__(256, 3) void out_gemm(
    const short* __restrict__ A, const short* __restrict__ Bt,
    const float* __restrict__ bo, float* __restrict__ Cout) {
  __shared__ short Asub[128 * 64];
  __shared__ short Bsub[128 * 64];
  const int tid = threadIdx.x;
  const int w = tid >> 6, lane = tid & 63, ln = lane & 15, quad = lane >> 4;
  const int row0 = blockIdx.x * 128, n0 = blockIdx.y * 128;
  const int wm = (w & 1) * 64, wn = (w >> 1) * 64;

  f32x4 acc[4][4];
  #pragma unroll
  for (int i = 0; i < 4; ++i)
    #pragma unroll
    for (int j = 0; j < 4; ++j) acc[i][j] = (f32x4){0.f, 0.f, 0.f, 0.f};

  for (int kt = 0; kt < 16; ++kt) {
    const int k0 = kt * 64;
    #pragma unroll
    for (int j = 0; j < 4; ++j) {
      int chunk = (w * 4 + j) * 64 + lane;
      int r = chunk >> 3, c = chunk & 7;
      const short* ga = A + (long)(row0 + r) * 1024 + k0 + c * 8;
      __builtin_amdgcn_global_load_lds(GA(ga), LA(&Asub[(w * 4 + j) * 512]), 16, 0, 0);
      const short* gb = Bt + (long)(n0 + r) * 1024 + k0 + c * 8;
      __builtin_amdgcn_global_load_lds(GA(gb), LA(&Bsub[(w * 4 + j) * 512]), 16, 0, 0);
    }
    __syncthreads();
    #pragma unroll
    for (int kk = 0; kk < 2; ++kk) {
      s16x8 af[4], bfr[4];
      #pragma unroll
      for (int i = 0; i < 4; ++i)
        af[i] = *(const s16x8*)&Asub[(wm + i * 16 + ln) * 64 + kk * 32 + quad * 8];
      #pragma unroll
      for (int j = 0; j < 4; ++j)
        bfr[j] = *(const s16x8*)&Bsub[(wn + j * 16 + ln) * 64 + kk * 32 + quad * 8];
      #pragma unroll
      for (int i = 0; i < 4; ++i)
        #pragma unroll
        for (int j = 0; j < 4; ++j)
          acc[i][j] = __builtin_amdgcn_mfma_f32_16x16x32_bf16(af[i], bfr[j], acc[i][j], 0, 0, 0);
    }
    __syncthreads();
  }
  #pragma unroll
  for (int j = 0; j < 4; ++j) {
    int n = n0 + wn + j * 16 + ln;
    float bvj = bo[n];
    #pragma unroll
    for (int i = 0; i < 4; ++i)
      #pragma unroll
      for (int r = 0; r < 4; ++r) {
        int row = row0 + wm + i * 16 + quad * 4 + r;
        Cout[(long)row * 1024 + n] = acc[i][j][r] + bvj;
      }
  }
}

// ---------------------------------------------------------------------------
extern "C" void kernel_launch(void* const* d_in, const int* in_sizes, int n_in,
                              void* d_out, int out_size, void* d_ws, size_t ws_size,
                              hipStream_t stream) {
  const float* query = (const float*)d_in[0];
  const float* key_  = (const float*)d_in[1];
  const float* value = (const float*)d_in[2];
  const float* abias = (const float*)d_in[3];
  const float* Wq = (const float*)d_in[4];
  const float* bq = (const float*)d_in[5];
  const float* Wk = (const float*)d_in[6];
  const float* bk = (const float*)d_in[7];
  const float* Wv = (const float*)d_in[8];
  const float* bv = (const float*)d_in[9];
  const float* Wo = (const float*)d_in[10];
  const float* bo = (const float*)d_in[11];
  float* out = (float*)d_out;

  char* ws = (char*)d_ws;
  short* WqkvT  = (short*)(ws);                 // 3072x1024 bf16  (6 MB)
  short* WoT    = (short*)(ws + 6291456);       // 1024x1024 bf16  (2 MB)
  short* qk     = (short*)(ws + 8388608);       // 8192x2048 bf16  (32 MB)
  short* VT     = (short*)(ws + 41943040);      // (b,h,d) x t bf16 (16 MB)
  short* concat = (short*)(ws + 58720256);      // 8192x1024 bf16  (16 MB)
  // fast path only: qkvb overlaps concat's region (dead by the time flash runs)
  short* qkvb   = (short*)(ws + 58720256);      // 3 x 8192x1024 bf16 (48 MB)
  const size_t need_fast = 58720256UL + 50331648UL;  // 104 MB

  dim3 tb(32, 8);
  transpose_cast<<<dim3(2, 32, 16), tb, 0, stream>>>(Wq, WqkvT,           1024, 64, 65536L, 65536L, SCALE_Q);
  transpose_cast<<<dim3(2, 32, 16), tb, 0, stream>>>(Wk, WqkvT + 1048576, 1024, 64, 65536L, 65536L, 1.0f);
  transpose_cast<<<dim3(2, 32, 16), tb, 0, stream>>>(Wv, WqkvT + 2097152, 1024, 64, 65536L, 65536L, 1.0f);
  transpose_cast<<<dim3(32, 32, 1), tb, 0, stream>>>(Wo, WoT,             1024, 1024, 0L, 0L, 1.0f);

  if (ws_size >= need_fast) {
    cast3_bf16<<<dim3(8192, 1, 3), 256, 0, stream>>>(query, key_, value, qkvb);
    proj_gemm_bf<<<dim3(64, 24), 256, 0, stream>>>(qkvb, qkvb + 8388608, qkvb + 16777216,
                                                   WqkvT, bq, bk, bv, qk, VT);
  } else {
    proj_gemm_f32<<<dim3(64, 24), 256, 0, stream>>>(query, key_, value, WqkvT, bq, bk, bv, qk, VT);
  }
  flash_attn<<<dim3(16, 16, 4), 256, 0, stream>>>(qk, VT, abias, concat);
  out_gemm<<<dim3(64, 8), 256, 0, stream>>>(concat, WoT, bo, out);
}

// Round 4
// 393.263 us; speedup vs baseline: 2.1113x; 1.0739x over previous
//
#include <hip/hip_runtime.h>

#define S_LEN 2048
#define E_DIM 1024
#define H_NUM 16

typedef __attribute__((ext_vector_type(8))) short s16x8;
typedef __attribute__((ext_vector_type(4))) float f32x4;
typedef __attribute__((ext_vector_type(4))) _Float16 h16x4;

#define GA(p) ((__attribute__((address_space(1))) void*)(p))
#define LA(p) ((__attribute__((address_space(3))) void*)(p))

#define LOG2E 1.4426950408889634f
#define SCALE_Q (0.125f * LOG2E)
#define SHIFT 12.0f   // folded into QK accumulator init; cancels in p/l

union cvt16 { int4 v; s16x8 s8; short e[8]; };

__device__ __forceinline__ short f2bf(float f) {  // RNE
  union { float f; unsigned u; } v; v.f = f;
  unsigned r = v.u + 0x7FFFu + ((v.u >> 16) & 1u);
  return (short)(r >> 16);
}
__device__ __forceinline__ short f2bf_fast(float f) {  // round-half-up (p >= 0)
  union { float f; unsigned u; } v; v.f = f;
  return (short)((v.u + 0x8000u) >> 16);
}

// ---------------------------------------------------------------------------
// Transpose + cast + scale: src fp32 (R x C) -> dst bf16 (C x R), batched.
// ---------------------------------------------------------------------------
__global__ void transpose_cast(const float* __restrict__ src, short* __restrict__ dst,
                               int R, int C, long sbs, long dbs, float scale) {
  __shared__ float tile[32][33];
  const float* s = src + (long)blockIdx.z * sbs;
  short* d = dst + (long)blockIdx.z * dbs;
  int c0 = blockIdx.x * 32, r0 = blockIdx.y * 32;
  #pragma unroll
  for (int i = threadIdx.y; i < 32; i += 8)
    tile[i][threadIdx.x] = s[(long)(r0 + i) * C + c0 + threadIdx.x];
  __syncthreads();
  #pragma unroll
  for (int i = threadIdx.y; i < 32; i += 8)
    d[(long)(c0 + i) * R + r0 + threadIdx.x] = f2bf(tile[threadIdx.x][i] * scale);
}

// ---------------------------------------------------------------------------
// Bias rearrange: biasR[q][b64 + ln*4 + nt] = (fp16) bias[q][b64 + nt*16 + ln]
// so flash's lane (quad,ln) reads its 4 nt-values as one 8B load.
// ---------------------------------------------------------------------------
__global__ void bias_rearrange(const float* __restrict__ bias, _Float16* __restrict__ biasR) {
  long tg = (long)blockIdx.x * 256 + threadIdx.x;
  long o = tg * 4;                      // output index, 4 halves per thread
  int q = (int)(o >> 11);
  int t = (int)(o & 2047);
  int b64 = t & ~63, u = t & 63, ln = u >> 2;
  const float* src = bias + (long)q * 2048 + b64 + ln;
  h16x4 hv;
  #pragma unroll
  for (int nt = 0; nt < 4; ++nt) hv[nt] = (_Float16)src[nt * 16];
  *(h16x4*)(biasR + o) = hv;
}

// ---------------------------------------------------------------------------
// QKV projection GEMM, fp32-A direct DMA staging (no precast, no fallback).
// A: fp32 (8192x1024) per segment, Bt: bf16 (3072x1024).
// Segs 0/1 -> qk (8192x2048); seg 2 -> VT [(b*16+h)*64+d][t].
// A-tile stored fp32 in LDS (32KB) with 16B-chunk XOR swizzle; converted to
// bf16 at fragment read. B-tile bf16 (16KB), same swizzle.
// ---------------------------------------------------------------------------
__global__ __launch_bounds__(256, 3) void proj_gemm(
    const float* __restrict__ Aq, const float* __restrict__ Ak, const float* __restrict__ Av,
    const short* __restrict__ Bt,
    const float* __restrict__ bq, const float* __restrict__ bk, const float* __restrict__ bv,
    short* __restrict__ qkOut, short* __restrict__ VT) {
  __shared__ float Asub[128 * 64];   // 32 KB, fp32, swizzled 16B chunks
  __shared__ short Bsub[128 * 64];   // 16 KB, bf16, swizzled 16B chunks
  const int tid = threadIdx.x;
  const int w = tid >> 6, lane = tid & 63, ln = lane & 15, quad = lane >> 4;
  const int row0 = blockIdx.x * 128, n0 = blockIdx.y * 128;
  const int seg = n0 >> 10;
  const float* A = (seg == 0) ? Aq : ((seg == 1) ? Ak : Av);
  const float* bptr = (seg == 0) ? bq : ((seg == 1) ? bk : bv);
  const float bscale = (seg == 0) ? SCALE_Q : 1.0f;
  const int nloc = n0 & 1023;
  const int wm = (w & 1) * 64, wn = (w >> 1) * 64;

  f32x4 acc[4][4];
  #pragma unroll
  for (int i = 0; i < 4; ++i)
    #pragma unroll
    for (int j = 0; j < 4; ++j) acc[i][j] = (f32x4){0.f, 0.f, 0.f, 0.f};

  for (int kt = 0; kt < 16; ++kt) {
    const int k0 = kt * 64;
    // B tile: 1024 chunks of 16B; slot s holds global chunk s^(r&7)
    #pragma unroll
    for (int j = 0; j < 4; ++j) {
      int ci = (w * 4 + j) * 64 + lane;
      int r = ci >> 3, s = ci & 7, g = s ^ (r & 7);
      const short* gb = Bt + (long)(n0 + r) * 1024 + k0 + g * 8;
      __builtin_amdgcn_global_load_lds(GA(gb), LA(&Bsub[ci * 8]), 16, 0, 0);
    }
    // A tile fp32: 2048 chunks of 16B; slot s holds chunk (s&8)|((s&7)^(r&7))
    #pragma unroll
    for (int it = 0; it < 8; ++it) {
      int ci = it * 256 + tid;
      int r = ci >> 4, s = ci & 15, g = (s & 8) | ((s & 7) ^ (r & 7));
      const float* ga = A + (long)(row0 + r) * 1024 + k0 + g * 4;
      __builtin_amdgcn_global_load_lds(GA(ga), LA(&Asub[ci * 4]), 16, 0, 0);
    }
    __syncthreads();
    #pragma unroll
    for (int kk = 0; kk < 2; ++kk) {
      s16x8 af[4], bfr[4];
      #pragma unroll
      for (int i = 0; i < 4; ++i) {
        int ra = wm + i * 16 + ln;
        int c0 = kk * 8 + quad * 2;
        int s0 = (c0 & 8) | ((c0 & 7) ^ (ra & 7));
        int c1 = c0 + 1;
        int s1 = (c1 & 8) | ((c1 & 7) ^ (ra & 7));
        f32x4 lo = *(const f32x4*)&Asub[ra * 64 + s0 * 4];
        f32x4 hi = *(const f32x4*)&Asub[ra * 64 + s1 * 4];
        s16x8 t;
        t[0] = f2bf(lo[0]); t[1] = f2bf(lo[1]); t[2] = f2bf(lo[2]); t[3] = f2bf(lo[3]);
        t[4] = f2bf(hi[0]); t[5] = f2bf(hi[1]); t[6] = f2bf(hi[2]); t[7] = f2bf(hi[3]);
        af[i] = t;
      }
      #pragma unroll
      for (int j = 0; j < 4; ++j) {
        int rb = wn + j * 16 + ln;
        int slot = (kk * 4 + quad) ^ (rb & 7);
        bfr[j] = *(const s16x8*)&Bsub[rb * 64 + slot * 8];
      }
      #pragma unroll
      for (int i = 0; i < 4; ++i)
        #pragma unroll
        for (int j = 0; j < 4; ++j)
          acc[i][j] = __builtin_amdgcn_mfma_f32_16x16x32_bf16(af[i], bfr[j], acc[i][j], 0, 0, 0);
    }
    __syncthreads();
  }
  if (seg < 2) {
    #pragma unroll
    for (int j = 0; j < 4; ++j) {
      float bvj = bptr[nloc + wn + j * 16 + ln] * bscale;
      int n = n0 + wn + j * 16 + ln;
      #pragma unroll
      for (int i = 0; i < 4; ++i)
        #pragma unroll
        for (int r = 0; r < 4; ++r) {
          int row = row0 + wm + i * 16 + quad * 4 + r;
          qkOut[(long)row * 2048 + n] = f2bf(acc[i][j][r] + bvj);
        }
    }
  } else {
    #pragma unroll
    for (int j = 0; j < 4; ++j) {
      int nl = nloc + wn + j * 16 + ln;
      int hh = nl >> 6, d = nl & 63;
      float bvj = bptr[nl];
      #pragma unroll
      for (int i = 0; i < 4; ++i) {
        int row = row0 + wm + i * 16 + quad * 4;
        int b = row >> 11, t = row & 2047;
        short4 sv;
        sv.x = f2bf(acc[i][j][0] + bvj);
        sv.y = f2bf(acc[i][j][1] + bvj);
        sv.z = f2bf(acc[i][j][2] + bvj);
        sv.w = f2bf(acc[i][j][3] + bvj);
        *(short4*)&VT[((long)(b * 16 + hh) * 64 + d) * 2048 + t] = sv;
      }
    }
  }
}

// ---------------------------------------------------------------------------
// Flash attention, shift-softmax, double-buffered DMA, XOR-swizzled LDS,
// fp16 rearranged bias (8 x 8B loads/iter). Grid (S/128, H, B).
// ---------------------------------------------------------------------------
__global__ __launch_bounds__(256, 3) void flash_attn(
    const short* __restrict__ qk, const short* __restrict__ VT,
    const _Float16* __restrict__ biasR, short* __restrict__ concat) {
  __shared__ short Ks[2][4096];   // (t, d) xor-swizzled 16B chunks
  __shared__ short Vs[2][4096];   // (d, t) xor-swizzled 16B chunks
  __shared__ short Ps[128 * 72];  // (qrow, t) pad 72
  const int tid = threadIdx.x;
  const int w = tid >> 6, lane = tid & 63, ln = lane & 15, quad = lane >> 4;
  const int q0 = blockIdx.x * 128;
  const int h = blockIdx.y, bb = blockIdx.z;

  s16x8 ones;
  #pragma unroll
  for (int e = 0; e < 8; ++e) ones[e] = (short)0x3F80;

  // Q fragments (pre-scaled by log2e/8 at prep)
  s16x8 qf[2][2];
  const short* qbase = qk + (long)(bb * 2048 + q0 + w * 32) * 2048 + h * 64;
  #pragma unroll
  for (int i = 0; i < 2; ++i)
    #pragma unroll
    for (int kk = 0; kk < 2; ++kk) {
      cvt16 u; u.v = *(const int4*)(qbase + (long)(i * 16 + ln) * 2048 + kk * 32 + quad * 8);
      qf[i][kk] = u.s8;
    }

  f32x4 o[2][4], lacc[2];
  #pragma unroll
  for (int i = 0; i < 2; ++i) {
    #pragma unroll
    for (int nt = 0; nt < 4; ++nt) o[i][nt] = (f32x4){0.f, 0.f, 0.f, 0.f};
    lacc[i] = (f32x4){0.f, 0.f, 0.f, 0.f};
  }

  const short* kbase = qk + (long)bb * 2048 * 2048 + 1024 + h * 64;
  const short* vbase = VT + (long)(bb * 16 + h) * 64 * 2048;
  const _Float16* bbase = biasR + (long)(q0 + w * 32 + quad * 4) * 2048 + ln * 4;

  // stage kv=0 into buffer 0
  #pragma unroll
  for (int j = 0; j < 2; ++j) {
    int ci = (w * 2 + j) * 64 + lane;
    int r = ci >> 3, cs = (ci & 7) ^ (r & 7);
    __builtin_amdgcn_global_load_lds(GA(kbase + (long)r * 2048 + cs * 8), LA(&Ks[0][(w * 2 + j) * 512]), 16, 0, 0);
    __builtin_amdgcn_global_load_lds(GA(vbase + (long)r * 2048 + cs * 8), LA(&Vs[0][(w * 2 + j) * 512]), 16, 0, 0);
  }

  for (int kv = 0; kv < 32; ++kv) {
    const int t0 = kv * 64, b = kv & 1;
    __syncthreads();  // own DMA drained pre-barrier -> buf b ready, buf b^1 free

    // bias loads for THIS iter (8 x 8B), issued before the prefetch DMAs
    h16x4 bld[2][4];
    #pragma unroll
    for (int i = 0; i < 2; ++i)
      #pragma unroll
      for (int r = 0; r < 4; ++r)
        bld[i][r] = *(const h16x4*)(bbase + (long)(i * 16 + r) * 2048 + t0);
    __builtin_amdgcn_sched_barrier(0);

    if (kv < 31) {  // prefetch kv+1 into other buffer
      const short* kb = kbase + (long)(t0 + 64) * 2048;
      const short* vb = vbase + (t0 + 64);
      #pragma unroll
      for (int j = 0; j < 2; ++j) {
        int ci = (w * 2 + j) * 64 + lane;
        int r = ci >> 3, cs = (ci & 7) ^ (r & 7);
        __builtin_amdgcn_global_load_lds(GA(kb + (long)r * 2048 + cs * 8), LA(&Ks[b ^ 1][(w * 2 + j) * 512]), 16, 0, 0);
        __builtin_amdgcn_global_load_lds(GA(vb + (long)r * 2048 + cs * 8), LA(&Vs[b ^ 1][(w * 2 + j) * 512]), 16, 0, 0);
      }
    }

    // scores (log2 domain, pre-shifted): sa = -SHIFT + (log2e/8) Q.K^T
    f32x4 sa[2][4];
    #pragma unroll
    for (int i = 0; i < 2; ++i)
      #pragma unroll
      for (int nt = 0; nt < 4; ++nt) sa[i][nt] = (f32x4){-SHIFT, -SHIFT, -SHIFT, -SHIFT};
    #pragma unroll
    for (int kk = 0; kk < 2; ++kk) {
      s16x8 bfr[4];
      #pragma unroll
      for (int nt = 0; nt < 4; ++nt)
        bfr[nt] = *(const s16x8*)&Ks[b][((nt * 16 + ln) << 6) + (((kk * 4 + quad) ^ (ln & 7)) << 3)];
      #pragma unroll
      for (int i = 0; i < 2; ++i)
        #pragma unroll
        for (int nt = 0; nt < 4; ++nt)
          sa[i][nt] = __builtin_amdgcn_mfma_f32_16x16x32_bf16(qf[i][kk], bfr[nt], sa[i][nt], 0, 0, 0);
    }

    // p = 2^(sa + bias*log2e); shift-invariant softmax, no max tracking
    #pragma unroll
    for (int i = 0; i < 2; ++i)
      #pragma unroll
      for (int r = 0; r < 4; ++r) {
        #pragma unroll
        for (int nt = 0; nt < 4; ++nt) {
          float bb_ = (float)bld[i][r][nt];
          float p = __builtin_amdgcn_exp2f(fmaf(bb_, LOG2E, sa[i][nt][r]));
          Ps[(w * 32 + i * 16 + quad * 4 + r) * 72 + nt * 16 + ln] = f2bf_fast(p);
        }
      }

    // O += P.V ; l += P.1  (Ps rows wave-private; same-wave LDS ordering ok)
    #pragma unroll
    for (int kk = 0; kk < 2; ++kk) {
      s16x8 pa[2], vbf[4];
      #pragma unroll
      for (int i = 0; i < 2; ++i)
        pa[i] = *(const s16x8*)&Ps[(w * 32 + i * 16 + ln) * 72 + kk * 32 + quad * 8];
      #pragma unroll
      for (int nt = 0; nt < 4; ++nt)
        vbf[nt] = *(const s16x8*)&Vs[b][((nt * 16 + ln) << 6) + (((kk * 4 + quad) ^ (ln & 7)) << 3)];
      #pragma unroll
      for (int i = 0; i < 2; ++i) {
        #pragma unroll
        for (int nt = 0; nt < 4; ++nt)
          o[i][nt] = __builtin_amdgcn_mfma_f32_16x16x32_bf16(pa[i], vbf[nt], o[i][nt], 0, 0, 0);
        lacc[i] = __builtin_amdgcn_mfma_f32_16x16x32_bf16(pa[i], ones, lacc[i], 0, 0, 0);
      }
    }
  }

  // epilogue: O / l -> concat
  #pragma unroll
  for (int i = 0; i < 2; ++i) {
    float inv[4];
    #pragma unroll
    for (int r = 0; r < 4; ++r) inv[r] = __builtin_amdgcn_rcpf(lacc[i][r]);
    long rowb = (long)bb * 2048 + q0 + w * 32 + i * 16 + quad * 4;
    #pragma unroll
    for (int nt = 0; nt < 4; ++nt)
      #pragma unroll
      for (int r = 0; r < 4; ++r)
        concat[(rowb + r) * 1024 + h * 64 + nt * 16 + ln] = f2bf(o[i][nt][r] * inv[r]);
  }
}

// ---------------------------------------------------------------------------
// Output GEMM: out[row, n] = sum_k concat[row, k] * WoT[n, k] + bo[n], fp32 out
// XOR-swizzled LDS (same pattern as proj's B tile) for both operands.
// ---------------------------------------------------------------------------
__global__ __launch_bounds__(256, 3) void out_gemm(
    const short* __restrict__ A, const short* __restrict__ Bt,
    const float* __restrict__ bo, float* __restrict__ Cout) {
  __shared__ short Asub[128 * 64];
  __shared__ short Bsub[128 * 64];
  const int tid = threadIdx.x;
  const int w = tid >> 6, lane = tid & 63, ln = lane & 15, quad = lane >> 4;
  const int row0 = blockIdx.x * 128, n0 = blockIdx.y * 128;
  const int wm = (w & 1) * 64, wn = (w >> 1) * 64;

  f32x4 acc[4][4];
  #pragma unroll
  for (int i = 0; i < 4; ++i)
    #pragma unroll
    for (int j = 0; j < 4; ++j) acc[i][j] = (f32x4){0.f, 0.f, 0.f, 0.f};

  for (int kt = 0; kt < 16; ++kt) {
    const int k0 = kt * 64;
    #pragma unroll
    for (int j = 0; j < 4; ++j) {
      int ci = (w * 4 + j) * 64 + lane;
      int r = ci >> 3, s = ci & 7, g = s ^ (r & 7);
      const short* ga = A + (long)(row0 + r) * 1024 + k0 + g * 8;
      __builtin_amdgcn_global_load_lds(GA(ga), LA(&Asub[ci * 8]), 16, 0, 0);
      const short* gb = Bt + (long)(n0 + r) * 1024 + k0 + g * 8;
      __builtin_amdgcn_global_load_lds(GA(gb), LA(&Bsub[ci * 8]), 16, 0, 0);
    }
    __syncthreads();
    #pragma unroll
    for (int kk = 0; kk < 2; ++kk) {
      s16x8 af[4], bfr[4];
      #pragma unroll
      for (int i = 0; i < 4; ++i) {
        int ra = wm + i * 16 + ln;
        int slot = (kk * 4 + quad) ^ (ra & 7);
        af[i] = *(const s16x8*)&Asub[ra * 64 + slot * 8];
      }
      #pragma unroll
      for (int j = 0; j < 4; ++j) {
        int rb = wn + j * 16 + ln;
        int slot = (kk * 4 + quad) ^ (rb & 7);
        bfr[j] = *(const s16x8*)&Bsub[rb * 64 + slot * 8];
      }
      #pragma unroll
      for (int i = 0; i < 4; ++i)
        #pragma unroll
        for (int j = 0; j < 4; ++j)
          acc[i][j] = __builtin_amdgcn_mfma_f32_16x16x32_bf16(af[i], bfr[j], acc[i][j], 0, 0, 0);
    }
    __syncthreads();
  }
  #pragma unroll
  for (int j = 0; j < 4; ++j) {
    int n = n0 + wn + j * 16 + ln;
    float bvj = bo[n];
    #pragma unroll
    for (int i = 0; i < 4; ++i)
      #pragma unroll
      for (int r = 0; r < 4; ++r) {
        int row = row0 + wm + i * 16 + quad * 4 + r;
        Cout[(long)row * 1024 + n] = acc[i][j][r] + bvj;
      }
  }
}

// ---------------------------------------------------------------------------
// ws layout (72 MB total, proven budget):
//   [ 0, 8M)  WqkvT bf16 (6MB) -> overwritten by biasR fp16 (8MB) after proj
//   [ 8,40M)  qk bf16 (8192 x 2048)
//   [40,56M)  VT bf16 [(b,h,d) x t] -> WoT bf16 (2MB) overwrites after flash
//   [56,72M)  concat bf16 (8192 x 1024)
// ---------------------------------------------------------------------------
extern "C" void kernel_launch(void* const* d_in, const int* in_sizes, int n_in,
                              void* d_out, int out_size, void* d_ws, size_t ws_size,
                              hipStream_t stream) {
  const float* query = (const float*)d_in[0];
  const float* key_  = (const float*)d_in[1];
  const float* value = (const float*)d_in[2];
  const float* abias = (const float*)d_in[3];
  const float* Wq = (const float*)d_in[4];
  const float* bq = (const float*)d_in[5];
  const float* Wk = (const float*)d_in[6];
  const float* bk = (const float*)d_in[7];
  const float* Wv = (const float*)d_in[8];
  const float* bv = (const float*)d_in[9];
  const float* Wo = (const float*)d_in[10];
  const float* bo = (const float*)d_in[11];
  float* out = (float*)d_out;

  char* ws = (char*)d_ws;
  short*    WqkvT  = (short*)(ws);
  _Float16* biasR  = (_Float16*)(ws);
  short*    qk     = (short*)(ws + 8388608);
  short*    VT     = (short*)(ws + 41943040);
  short*    WoT    = (short*)(ws + 41943040);
  short*    concat = (short*)(ws + 58720256);

  dim3 tb(32, 8);
  transpose_cast<<<dim3(2, 32, 16), tb, 0, stream>>>(Wq, WqkvT,           1024, 64, 65536L, 65536L, SCALE_Q);
  transpose_cast<<<dim3(2, 32, 16), tb, 0, stream>>>(Wk, WqkvT + 1048576, 1024, 64, 65536L, 65536L, 1.0f);
  transpose_cast<<<dim3(2, 32, 16), tb, 0, stream>>>(Wv, WqkvT + 2097152, 1024, 64, 65536L, 65536L, 1.0f);
  proj_gemm<<<dim3(64, 24), 256, 0, stream>>>(query, key_, value, WqkvT, bq, bk, bv, qk, VT);
  bias_rearrange<<<dim3(4096), 256, 0, stream>>>(abias, biasR);
  flash_attn<<<dim3(16, 16, 4), 256, 0, stream>>>(qk, VT, biasR, concat);
  transpose_cast<<<dim3(32, 32, 1), tb, 0, stream>>>(Wo, WoT, 1024, 1024, 0L, 0L, 1.0f);
  out_gemm<<<dim3(64, 8), 256, 0, stream>>>(concat, WoT, bo, out);
}